// Round 7
// baseline (382.092 us; speedup 1.0000x reference)
//
#include <hip/hip_runtime.h>

#define NN 50000
#define EE 800000
#define ETOT (EE + NN)
#define GG 256
#define LL 3
#define HH 4
#define DD 128
#define NBLK ((NN + 255) / 256)   // 196
#define NXCD 8
#define DPX ((NN + NXCD - 1) / NXCD)  // 6250
#define CSRB 1024
#define GB ((NN + 63) / 64)       // 782 gemm blocks

#define NEG_SENT (-1e30f)

typedef __attribute__((ext_vector_type(8))) short s16x8;
typedef __attribute__((ext_vector_type(4))) float f32x4;
union U4 { uint4 u; s16x8 s; };

// float -> bf16 bits (round-nearest-even), finite inputs.
__device__ __forceinline__ unsigned short f2bf(float x) {
  unsigned u = __float_as_uint(x);
  unsigned r = u + 0x7FFFu + ((u >> 16) & 1u);
  return (unsigned short)(r >> 16);
}
__device__ __forceinline__ float bf2f(unsigned short b) {
  return __uint_as_float((unsigned)b << 16);
}

// ---- W^T split into bf16 hi/lo, [l][n][k] layout (once) ----
__global__ __launch_bounds__(256) void wsplit_k(const float* __restrict__ W,
                                                unsigned short* __restrict__ Wth,
                                                unsigned short* __restrict__ Wtl) {
  int i = blockIdx.x * 256 + threadIdx.x;
  if (i >= LL * DD * DD) return;
  int l = i / (DD * DD), rem = i % (DD * DD);
  int n = rem >> 7, k = rem & 127;
  float w = W[(size_t)l * DD * DD + k * DD + n];
  unsigned short hb = f2bf(w);
  Wth[i] = hb;
  Wtl[i] = f2bf(w - bf2f(hb));
}

// ---- MFMA GEMM (split-bf16, fp32-grade) + attention-logit epilogue ----
// One wave = 16 rows x 128 cols; 4 waves/block = 64 rows. LDS-free.
// A mapping: row=lane&15, k=(lane>>4)*8+e ; B: col=lane&15, same k.
// C/D: col=lane&15, row=(lane>>4)*4+reg  [verified layout].
template <int L0>
__global__ __launch_bounds__(256) void gemm_mfma_k(const float* __restrict__ Ax,
                                                   const unsigned short* __restrict__ Ahi,
                                                   const unsigned short* __restrict__ Alo,
                                                   const unsigned short* __restrict__ Wth,
                                                   const unsigned short* __restrict__ Wtl,
                                                   const float* __restrict__ asrc,
                                                   const float* __restrict__ adst,
                                                   unsigned short* __restrict__ Hb,
                                                   float* __restrict__ al_s,
                                                   float* __restrict__ al_d) {
  int wid = threadIdx.x >> 6, lane = threadIdx.x & 63;
  int r0 = blockIdx.x * 64 + wid * 16;
  int c0 = lane & 15, kg = lane >> 4;
  int row = r0 + c0;
  int rl = row < NN ? row : NN - 1;
  f32x4 acc[8];
#pragma unroll
  for (int nt = 0; nt < 8; ++nt) acc[nt] = (f32x4){0.f, 0.f, 0.f, 0.f};

#pragma unroll
  for (int ks = 0; ks < 4; ++ks) {
    s16x8 ah, al;
    if (L0) {
      const float* ap = &Ax[(size_t)rl * DD + ks * 32 + kg * 8];
      float4 v0 = *(const float4*)ap;
      float4 v1 = *(const float4*)(ap + 4);
      float av[8] = {v0.x, v0.y, v0.z, v0.w, v1.x, v1.y, v1.z, v1.w};
#pragma unroll
      for (int e = 0; e < 8; ++e) {
        unsigned short hb = f2bf(av[e]);
        ah[e] = (short)hb;
        al[e] = (short)f2bf(av[e] - bf2f(hb));
      }
    } else {
      U4 uh, ul;
      uh.u = *(const uint4*)&Ahi[(size_t)rl * DD + ks * 32 + kg * 8];
      ul.u = *(const uint4*)&Alo[(size_t)rl * DD + ks * 32 + kg * 8];
      ah = uh.s;
      al = ul.s;
    }
#pragma unroll
    for (int nt = 0; nt < 8; ++nt) {
      int wrow = nt * 16 + c0;
      U4 wh, wl;
      wh.u = *(const uint4*)&Wth[(size_t)wrow * DD + ks * 32 + kg * 8];
      wl.u = *(const uint4*)&Wtl[(size_t)wrow * DD + ks * 32 + kg * 8];
      acc[nt] = __builtin_amdgcn_mfma_f32_16x16x32_bf16(ah, wh.s, acc[nt], 0, 0, 0);
      acc[nt] = __builtin_amdgcn_mfma_f32_16x16x32_bf16(al, wh.s, acc[nt], 0, 0, 0);
      acc[nt] = __builtin_amdgcn_mfma_f32_16x16x32_bf16(ah, wl.s, acc[nt], 0, 0, 0);
    }
  }

  // ---- epilogue: per-head logits (fp32 acc) + bf16 Hb write ----
  float ps[4][4] = {}, pd[4][4] = {};
#pragma unroll
  for (int nt = 0; nt < 8; ++nt) {
    int col = nt * 16 + c0;
    float sv = asrc[col], dv = adst[col];
    int hg = nt >> 1;
#pragma unroll
    for (int r = 0; r < 4; ++r) {
      ps[hg][r] += acc[nt][r] * sv;
      pd[hg][r] += acc[nt][r] * dv;
    }
  }
#pragma unroll
  for (int off = 1; off < 16; off <<= 1) {
#pragma unroll
    for (int h = 0; h < 4; ++h)
#pragma unroll
      for (int r = 0; r < 4; ++r) {
        ps[h][r] += __shfl_xor(ps[h][r], off);
        pd[h][r] += __shfl_xor(pd[h][r], off);
      }
  }
#pragma unroll
  for (int r = 0; r < 4; ++r) {
    int grr = r0 + kg * 4 + r;
    if (grr < NN) {
#pragma unroll
      for (int nt = 0; nt < 8; ++nt)
        Hb[(size_t)grr * DD + nt * 16 + c0] = f2bf(acc[nt][r]);
      if (c0 == 0) {
#pragma unroll
        for (int h = 0; h < 4; ++h) {
          al_s[grr * 4 + h] = ps[h][r];
          al_d[grr * 4 + h] = pd[h][r];
        }
      }
    }
  }
}

// ---- CSR build: XCD-affine dst-range partitioning ----
__global__ __launch_bounds__(256) void deg_k(const int* __restrict__ ei,
                                             int* __restrict__ deg) {
  int lo = (blockIdx.x & 7) * DPX, hi = lo + DPX;
  int stride = (gridDim.x >> 3) * 256;
  for (int e = (blockIdx.x >> 3) * 256 + threadIdx.x; e < ETOT; e += stride) {
    int d = (e < EE) ? ei[EE + e] : (e - EE);
    if (d >= lo && d < hi) atomicAdd(&deg[d], 1);
  }
}

__global__ __launch_bounds__(256) void scanA_k(const int* __restrict__ deg,
                                               int* __restrict__ rp,
                                               int* __restrict__ bsum) {
  __shared__ int sb[256];
  int t = threadIdx.x, b = blockIdx.x, i = b * 256 + t;
  int d = (i < NN) ? deg[i] : 0;
  sb[t] = d;
  __syncthreads();
#pragma unroll
  for (int off = 1; off < 256; off <<= 1) {
    int v = (t >= off) ? sb[t - off] : 0;
    __syncthreads();
    sb[t] += v;
    __syncthreads();
  }
  if (i < NN) rp[i] = sb[t] - d;
  if (t == 255) bsum[b] = sb[255];
}

__global__ __launch_bounds__(256) void scanB_k(const int* __restrict__ bsum,
                                               int* __restrict__ boff) {
  __shared__ int sb[256];
  int t = threadIdx.x;
  int d = (t < NBLK) ? bsum[t] : 0;
  sb[t] = d;
  __syncthreads();
#pragma unroll
  for (int off = 1; off < 256; off <<= 1) {
    int v = (t >= off) ? sb[t - off] : 0;
    __syncthreads();
    sb[t] += v;
    __syncthreads();
  }
  if (t < NBLK) boff[t] = sb[t] - d;
}

__global__ __launch_bounds__(256) void scanC_k(int* __restrict__ rp,
                                               const int* __restrict__ boff,
                                               int* __restrict__ cur) {
  int b = blockIdx.x, i = b * 256 + threadIdx.x;
  if (i < NN) {
    int v = rp[i] + boff[b];
    rp[i] = v;
    cur[i] = v;
  }
  if (i == 0) rp[NN] = ETOT;
}

__global__ __launch_bounds__(256) void scatter_k(const int* __restrict__ ei,
                                                 int* __restrict__ cur,
                                                 int* __restrict__ col) {
  int lo = (blockIdx.x & 7) * DPX, hi = lo + DPX;
  int stride = (gridDim.x >> 3) * 256;
  for (int e = (blockIdx.x >> 3) * 256 + threadIdx.x; e < ETOT; e += stride) {
    int s, d;
    if (e < EE) { s = ei[e]; d = ei[EE + e]; }
    else        { s = e - EE; d = s; }
    if (d >= lo && d < hi) {
      int pos = atomicAdd(&cur[d], 1);
      col[pos] = s;
    }
  }
}

__global__ __launch_bounds__(64) void gstart_k(const int* __restrict__ batch,
                                               int* __restrict__ gs) {
  int g = blockIdx.x * 64 + threadIdx.x;
  if (g > GG) return;
  int lo = 0, hi = NN;
  while (lo < hi) {
    int mid = (lo + hi) >> 1;
    if (batch[mid] < g) lo = mid + 1; else hi = mid;
  }
  gs[g] = lo;
}

// ---- Fused per-node: segment-softmax + weighted agg (bf16 gather) + bias+LN+LeakyReLU ----
// Output written as split bf16 hi/lo pair (fp32-grade for the next GEMM).
__global__ __launch_bounds__(256) void agg_k(const int* __restrict__ rp,
                                             const int* __restrict__ col,
                                             const float* __restrict__ als,
                                             const float* __restrict__ ald,
                                             const unsigned short* __restrict__ Hb,
                                             const float* __restrict__ bias,
                                             const float* __restrict__ gamma,
                                             const float* __restrict__ beta,
                                             unsigned short* __restrict__ ABh,
                                             unsigned short* __restrict__ ABl) {
  __shared__ float salpha[4][4][65];
  __shared__ int   scol[4][64];
  int wave = threadIdx.x >> 6, lane = threadIdx.x & 63;
  int n = blockIdx.x * 4 + wave;
  if (n >= NN) return;
  int e0 = rp[n], e1 = rp[n + 1];
  int deg = e1 - e0;
  float4 ad = *(const float4*)&ald[(size_t)n * 4];
  int hh = lane >> 4;
  float a0 = 0.f, a1 = 0.f;

  if (deg <= 64) {
    int sn = (lane < deg) ? col[e0 + lane] : -1;
    float4 as;
    if (sn >= 0) as = *(const float4*)&als[(size_t)sn * 4];
    else         as = make_float4(0.f, 0.f, 0.f, 0.f);
    float vv[4] = {as.x + ad.x, as.y + ad.y, as.z + ad.z, as.w + ad.w};
#pragma unroll
    for (int h = 0; h < 4; ++h) {
      float t = vv[h];
      t = t > 0.f ? t : 0.2f * t;
      vv[h] = (sn >= 0) ? t : NEG_SENT;
    }
    float m[4] = {vv[0], vv[1], vv[2], vv[3]};
#pragma unroll
    for (int off = 32; off; off >>= 1) {
#pragma unroll
      for (int h = 0; h < 4; ++h) m[h] = fmaxf(m[h], __shfl_xor(m[h], off));
    }
    float p[4], s[4];
#pragma unroll
    for (int h = 0; h < 4; ++h) {
      p[h] = (sn >= 0) ? __expf(vv[h] - m[h]) : 0.f;
      s[h] = p[h];
    }
#pragma unroll
    for (int off = 32; off; off >>= 1) {
#pragma unroll
      for (int h = 0; h < 4; ++h) s[h] += __shfl_xor(s[h], off);
    }
    scol[wave][lane] = sn;
#pragma unroll
    for (int h = 0; h < 4; ++h)
      salpha[wave][h][lane] = __fdividef(p[h], s[h]);
    asm volatile("s_waitcnt lgkmcnt(0)" ::: "memory");
#pragma unroll 4
    for (int j = 0; j < deg; ++j) {
      int snj = scol[wave][j];
      float alpha = salpha[wave][hh][j];
      unsigned pck = *(const unsigned*)&Hb[(size_t)snj * DD + 2 * lane];
      float h0 = __uint_as_float(pck << 16);
      float h1 = __uint_as_float(pck & 0xFFFF0000u);
      a0 = __fmaf_rn(alpha, h0, a0);
      a1 = __fmaf_rn(alpha, h1, a1);
    }
  } else {
    float m[4] = {NEG_SENT, NEG_SENT, NEG_SENT, NEG_SENT};
    float s[4] = {0.f, 0.f, 0.f, 0.f};
    for (int e = e0 + lane; e < e1; e += 64) {
      int sn = col[e];
      float4 as = *(const float4*)&als[(size_t)sn * 4];
      float v[4] = {as.x + ad.x, as.y + ad.y, as.z + ad.z, as.w + ad.w};
#pragma unroll
      for (int h = 0; h < 4; ++h) {
        float vvv = v[h] > 0.f ? v[h] : 0.2f * v[h];
        if (vvv > m[h]) { s[h] = s[h] * __expf(m[h] - vvv) + 1.f; m[h] = vvv; }
        else             s[h] += __expf(vvv - m[h]);
      }
    }
#pragma unroll
    for (int off = 32; off; off >>= 1) {
#pragma unroll
      for (int h = 0; h < 4; ++h) {
        float mo = __shfl_xor(m[h], off);
        float so = __shfl_xor(s[h], off);
        float M = fmaxf(m[h], mo);
        s[h] = s[h] * __expf(m[h] - M) + so * __expf(mo - M);
        m[h] = M;
      }
    }
    float mh = m[hh];
    float rdh = __fdividef(1.f, s[hh]);
    float adh = (hh == 0) ? ad.x : (hh == 1) ? ad.y : (hh == 2) ? ad.z : ad.w;
    int e = e0;
    while (e < e1) {
      int cnt = min(64, e1 - e);
      int myS = (lane < cnt) ? col[e + lane] : 0;
      for (int j = 0; j < cnt; ++j) {
        int sn = __shfl(myS, j);
        float v = als[(size_t)sn * 4 + hh] + adh;
        v = v > 0.f ? v : 0.2f * v;
        float alpha = __expf(v - mh) * rdh;
        unsigned pck = *(const unsigned*)&Hb[(size_t)sn * DD + 2 * lane];
        float h0 = __uint_as_float(pck << 16);
        float h1 = __uint_as_float(pck & 0xFFFF0000u);
        a0 = __fmaf_rn(alpha, h0, a0);
        a1 = __fmaf_rn(alpha, h1, a1);
      }
      e += cnt;
    }
  }

  int f0 = 2 * lane, f1 = 2 * lane + 1;
  float x0 = a0 + bias[f0], x1 = a1 + bias[f1];
  float sum = x0 + x1, ssq = x0 * x0 + x1 * x1;
#pragma unroll
  for (int off = 32; off; off >>= 1) {
    sum += __shfl_xor(sum, off);
    ssq += __shfl_xor(ssq, off);
  }
  float mu = sum * (1.f / 128.f);
  float var = ssq * (1.f / 128.f) - mu * mu;
  float rstd = rsqrtf(var + 1e-5f);
  float y0 = (x0 - mu) * rstd * gamma[f0] + beta[f0];
  float y1 = (x1 - mu) * rstd * gamma[f1] + beta[f1];
  y0 = y0 > 0.f ? y0 : 0.1f * y0;
  y1 = y1 > 0.f ? y1 : 0.1f * y1;
  unsigned short h0b = f2bf(y0), h1b = f2bf(y1);
  unsigned short l0b = f2bf(y0 - bf2f(h0b)), l1b = f2bf(y1 - bf2f(h1b));
  *(unsigned*)&ABh[(size_t)n * DD + f0] = (unsigned)h0b | ((unsigned)h1b << 16);
  *(unsigned*)&ABl[(size_t)n * DD + f0] = (unsigned)l0b | ((unsigned)l1b << 16);
}

// ---- Fused pooling + output GEMM (reads split hi/lo) ----
__global__ __launch_bounds__(128) void poolout_k(const unsigned short* __restrict__ ABh,
                                                 const unsigned short* __restrict__ ABl,
                                                 const int* __restrict__ gs,
                                                 const float* __restrict__ Wout,
                                                 const float* __restrict__ bout,
                                                 float* __restrict__ out) {
  __shared__ float sp[256];
  int g = blockIdx.x, t = threadIdx.x;
  int n0 = gs[g], n1 = gs[g + 1];
  float mx = NEG_SENT, sm = 0.f;
#pragma unroll 4
  for (int n = n0; n < n1; ++n) {
    float v = bf2f(ABh[(size_t)n * DD + t]) + bf2f(ABl[(size_t)n * DD + t]);
    mx = fmaxf(mx, v);
    sm += v;
  }
  float c = (float)(n1 - n0);
  sp[t] = mx;
  sp[128 + t] = sm / fmaxf(c, 1.f);
  __syncthreads();
  float acc = bout[t];
#pragma unroll 8
  for (int k = 0; k < 256; ++k) acc = __fmaf_rn(sp[k], Wout[k * 128 + t], acc);
  out[(size_t)g * 128 + t] = acc;
}

extern "C" void kernel_launch(void* const* d_in, const int* in_sizes, int n_in,
                              void* d_out, int out_size, void* d_ws, size_t ws_size,
                              hipStream_t stream) {
  const float* x       = (const float*)d_in[0];
  const int*   ei      = (const int*)d_in[1];
  const int*   batch   = (const int*)d_in[2];
  const float* W       = (const float*)d_in[3];
  const float* att_src = (const float*)d_in[4];
  const float* att_dst = (const float*)d_in[5];
  const float* bias    = (const float*)d_in[6];
  const float* gamma   = (const float*)d_in[7];
  const float* beta    = (const float*)d_in[8];
  const float* Wout    = (const float*)d_in[9];
  const float* bout    = (const float*)d_in[10];
  float* out = (float*)d_out;

  char* ws = (char*)d_ws;
  unsigned short* Hb  = (unsigned short*)ws; ws += (size_t)NN * DD * 2;
  unsigned short* ABh = (unsigned short*)ws; ws += (size_t)NN * DD * 2;
  unsigned short* ABl = (unsigned short*)ws; ws += (size_t)NN * DD * 2;
  unsigned short* Wth = (unsigned short*)ws; ws += (size_t)LL * DD * DD * 2;
  unsigned short* Wtl = (unsigned short*)ws; ws += (size_t)LL * DD * DD * 2;
  float* als  = (float*)ws; ws += (size_t)NN * HH * 4;
  float* ald  = (float*)ws; ws += (size_t)NN * HH * 4;
  int*   rp   = (int*)ws;   ws += (size_t)(NN + 1) * 4;
  int*   deg  = (int*)ws;   ws += (size_t)NN * 4;      // reused as scatter cursor
  int*   col  = (int*)ws;   ws += (size_t)ETOT * 4;
  int*   gs   = (int*)ws;   ws += (size_t)(GG + 1) * 4;
  int*   bsum = (int*)ws;   ws += (size_t)NBLK * 4;
  int*   boff = (int*)ws;   ws += (size_t)NBLK * 4;

  // ---- CSR build + graph offsets + W split (once) ----
  hipMemsetAsync(deg, 0, (size_t)NN * 4, stream);
  deg_k<<<CSRB, 256, 0, stream>>>(ei, deg);
  scanA_k<<<NBLK, 256, 0, stream>>>(deg, rp, bsum);
  scanB_k<<<1, 256, 0, stream>>>(bsum, boff);
  scanC_k<<<NBLK, 256, 0, stream>>>(rp, boff, deg);
  scatter_k<<<CSRB, 256, 0, stream>>>(ei, deg, col);
  gstart_k<<<(GG + 1 + 63) / 64, 64, 0, stream>>>(batch, gs);
  wsplit_k<<<(LL * DD * DD + 255) / 256, 256, 0, stream>>>(W, Wth, Wtl);

  // ---- layers ----
  for (int l = 0; l < LL; ++l) {
    const unsigned short* Wh = Wth + (size_t)l * DD * DD;
    const unsigned short* Wl = Wtl + (size_t)l * DD * DD;
    if (l == 0)
      gemm_mfma_k<1><<<GB, 256, 0, stream>>>(x, ABh, ABl, Wh, Wl,
                                             att_src + l * DD, att_dst + l * DD,
                                             Hb, als, ald);
    else
      gemm_mfma_k<0><<<GB, 256, 0, stream>>>(x, ABh, ABl, Wh, Wl,
                                             att_src + l * DD, att_dst + l * DD,
                                             Hb, als, ald);
    agg_k<<<(NN + 3) / 4, 256, 0, stream>>>(rp, col, als, ald, Hb,
                                            bias + l * DD, gamma + l * DD, beta + l * DD,
                                            ABh, ABl);
  }

  // ---- fused pooling + output GEMM ----
  poolout_k<<<GG, 128, 0, stream>>>(ABh, ABl, gs, Wout, bout, out);
}

// Round 8
// 369.975 us; speedup vs baseline: 1.0328x; 1.0328x over previous
//
#include <hip/hip_runtime.h>

#define NN 50000
#define EE 800000
#define ETOT (EE + NN)
#define GG 256
#define LL 3
#define HH 4
#define DD 128
#define NBLK ((NN + 255) / 256)   // 196
#define NXCD 8
#define DPX ((NN + NXCD - 1) / NXCD)  // 6250
#define CSRB 1024

#define NEG_SENT (-1e30f)

// float -> bf16 bits (round-nearest-even), finite inputs.
__device__ __forceinline__ unsigned short f2bf(float x) {
  unsigned u = __float_as_uint(x);
  unsigned r = u + 0x7FFFu + ((u >> 16) & 1u);
  return (unsigned short)(r >> 16);
}

// ---- GEMM + attention-logit epilogue (scalar fp32, proven round-6 version) ----
__global__ __launch_bounds__(256) void gemm_al_k(const float* __restrict__ A,
                                                 const float* __restrict__ Wl,
                                                 const float* __restrict__ asrc,
                                                 const float* __restrict__ adst,
                                                 unsigned short* __restrict__ Hb,
                                                 float* __restrict__ al_s,
                                                 float* __restrict__ al_d) {
  __shared__ float sW[128 * 128];   // 64 KB
  __shared__ float sA[32][128];     // 16 KB
  int tid = threadIdx.x;
#pragma unroll
  for (int j = 0; j < 16; ++j) {
    int idx = j * 256 + tid;
    *(float4*)&sW[idx * 4] = *(const float4*)&Wl[idx * 4];
  }
  int row0 = blockIdx.x * 32;
#pragma unroll
  for (int j = 0; j < 4; ++j) {
    int idx = j * 256 + tid;
    int r = idx >> 5, c4 = idx & 31;
    int gr = row0 + r;
    float4 v = (gr < NN) ? *(const float4*)&A[(size_t)gr * DD + c4 * 4]
                         : make_float4(0.f, 0.f, 0.f, 0.f);
    *(float4*)&sA[r][c4 * 4] = v;
  }
  __syncthreads();
  int tc = tid & 31;
  int tr = tid >> 5;
  float acc[4][4] = {};
  for (int k = 0; k < 128; ++k) {
    float4 w = *(const float4*)&sW[k * 128 + tc * 4];
    float a[4];
#pragma unroll
    for (int r = 0; r < 4; ++r) a[r] = sA[tr * 4 + r][k];
#pragma unroll
    for (int r = 0; r < 4; ++r) {
      acc[r][0] += a[r] * w.x;
      acc[r][1] += a[r] * w.y;
      acc[r][2] += a[r] * w.z;
      acc[r][3] += a[r] * w.w;
    }
  }
  float4 as4 = *(const float4*)&asrc[tc * 4];
  float4 ad4 = *(const float4*)&adst[tc * 4];
  int hg = tc >> 3;
  float ps[4], pd[4];
#pragma unroll
  for (int r = 0; r < 4; ++r) {
    ps[r] = acc[r][0] * as4.x + acc[r][1] * as4.y + acc[r][2] * as4.z + acc[r][3] * as4.w;
    pd[r] = acc[r][0] * ad4.x + acc[r][1] * ad4.y + acc[r][2] * ad4.z + acc[r][3] * ad4.w;
  }
#pragma unroll
  for (int off = 4; off; off >>= 1) {
#pragma unroll
    for (int r = 0; r < 4; ++r) {
      ps[r] += __shfl_xor(ps[r], off);
      pd[r] += __shfl_xor(pd[r], off);
    }
  }
#pragma unroll
  for (int r = 0; r < 4; ++r) {
    int gr = row0 + tr * 4 + r;
    if (gr < NN) {
      unsigned lo = (unsigned)f2bf(acc[r][0]) | ((unsigned)f2bf(acc[r][1]) << 16);
      unsigned hi = (unsigned)f2bf(acc[r][2]) | ((unsigned)f2bf(acc[r][3]) << 16);
      uint2 w = {lo, hi};
      *(uint2*)&Hb[(size_t)gr * DD + tc * 4] = w;
      if ((tc & 7) == 0) {
        al_s[gr * 4 + hg] = ps[r];
        al_d[gr * 4 + hg] = pd[r];
      }
    }
  }
}

// ---- CSR build: XCD-affine dst-range partitioning ----
__global__ __launch_bounds__(256) void deg_k(const int* __restrict__ ei,
                                             int* __restrict__ deg) {
  int lo = (blockIdx.x & 7) * DPX, hi = lo + DPX;
  int stride = (gridDim.x >> 3) * 256;
  for (int e = (blockIdx.x >> 3) * 256 + threadIdx.x; e < ETOT; e += stride) {
    int d = (e < EE) ? ei[EE + e] : (e - EE);
    if (d >= lo && d < hi) atomicAdd(&deg[d], 1);
  }
}

__global__ __launch_bounds__(256) void scanA_k(const int* __restrict__ deg,
                                               int* __restrict__ rp,
                                               int* __restrict__ bsum) {
  __shared__ int sb[256];
  int t = threadIdx.x, b = blockIdx.x, i = b * 256 + t;
  int d = (i < NN) ? deg[i] : 0;
  sb[t] = d;
  __syncthreads();
#pragma unroll
  for (int off = 1; off < 256; off <<= 1) {
    int v = (t >= off) ? sb[t - off] : 0;
    __syncthreads();
    sb[t] += v;
    __syncthreads();
  }
  if (i < NN) rp[i] = sb[t] - d;
  if (t == 255) bsum[b] = sb[255];
}

__global__ __launch_bounds__(256) void scanB_k(const int* __restrict__ bsum,
                                               int* __restrict__ boff) {
  __shared__ int sb[256];
  int t = threadIdx.x;
  int d = (t < NBLK) ? bsum[t] : 0;
  sb[t] = d;
  __syncthreads();
#pragma unroll
  for (int off = 1; off < 256; off <<= 1) {
    int v = (t >= off) ? sb[t - off] : 0;
    __syncthreads();
    sb[t] += v;
    __syncthreads();
  }
  if (t < NBLK) boff[t] = sb[t] - d;
}

__global__ __launch_bounds__(256) void scanC_k(int* __restrict__ rp,
                                               const int* __restrict__ boff,
                                               int* __restrict__ cur) {
  int b = blockIdx.x, i = b * 256 + threadIdx.x;
  if (i < NN) {
    int v = rp[i] + boff[b];
    rp[i] = v;
    cur[i] = v;
  }
  if (i == 0) rp[NN] = ETOT;
}

__global__ __launch_bounds__(256) void scatter_k(const int* __restrict__ ei,
                                                 int* __restrict__ cur,
                                                 int* __restrict__ col) {
  int lo = (blockIdx.x & 7) * DPX, hi = lo + DPX;
  int stride = (gridDim.x >> 3) * 256;
  for (int e = (blockIdx.x >> 3) * 256 + threadIdx.x; e < ETOT; e += stride) {
    int s, d;
    if (e < EE) { s = ei[e]; d = ei[EE + e]; }
    else        { s = e - EE; d = s; }
    if (d >= lo && d < hi) {
      int pos = atomicAdd(&cur[d], 1);
      col[pos] = s;
    }
  }
}

__global__ __launch_bounds__(64) void gstart_k(const int* __restrict__ batch,
                                               int* __restrict__ gs) {
  int g = blockIdx.x * 64 + threadIdx.x;
  if (g > GG) return;
  int lo = 0, hi = NN;
  while (lo < hi) {
    int mid = (lo + hi) >> 1;
    if (batch[mid] < g) lo = mid + 1; else hi = mid;
  }
  gs[g] = lo;
}

// ---- Fused per-node: segment-softmax + weighted agg (bf16 gather) + bias+LN+LeakyReLU ----
// Fast-path gather: 2 edges/iter, 32 lanes x 4 feats each (2x miss-level parallelism).
__global__ __launch_bounds__(256) void agg_k(const int* __restrict__ rp,
                                             const int* __restrict__ col,
                                             const float* __restrict__ als,
                                             const float* __restrict__ ald,
                                             const unsigned short* __restrict__ Hb,
                                             const float* __restrict__ bias,
                                             const float* __restrict__ gamma,
                                             const float* __restrict__ beta,
                                             float* __restrict__ outb) {
  __shared__ float salpha[4][4][65];
  __shared__ int   scol[4][64];
  int wave = threadIdx.x >> 6, lane = threadIdx.x & 63;
  int n = blockIdx.x * 4 + wave;
  if (n >= NN) return;
  int e0 = rp[n], e1 = rp[n + 1];
  int deg = e1 - e0;
  float4 ad = *(const float4*)&ald[(size_t)n * 4];

  if (deg <= 64) {
    // --- softmax: one edge per lane ---
    int sn = (lane < deg) ? col[e0 + lane] : -1;
    float4 as;
    if (sn >= 0) as = *(const float4*)&als[(size_t)sn * 4];
    else         as = make_float4(0.f, 0.f, 0.f, 0.f);
    float vv[4] = {as.x + ad.x, as.y + ad.y, as.z + ad.z, as.w + ad.w};
#pragma unroll
    for (int h = 0; h < 4; ++h) {
      float t = vv[h];
      t = t > 0.f ? t : 0.2f * t;
      vv[h] = (sn >= 0) ? t : NEG_SENT;
    }
    float m[4] = {vv[0], vv[1], vv[2], vv[3]};
#pragma unroll
    for (int off = 32; off; off >>= 1) {
#pragma unroll
      for (int h = 0; h < 4; ++h) m[h] = fmaxf(m[h], __shfl_xor(m[h], off));
    }
    float p[4], s[4];
#pragma unroll
    for (int h = 0; h < 4; ++h) {
      p[h] = (sn >= 0) ? __expf(vv[h] - m[h]) : 0.f;
      s[h] = p[h];
    }
#pragma unroll
    for (int off = 32; off; off >>= 1) {
#pragma unroll
      for (int h = 0; h < 4; ++h) s[h] += __shfl_xor(s[h], off);
    }
    scol[wave][lane] = sn;
#pragma unroll
    for (int h = 0; h < 4; ++h)
      salpha[wave][h][lane] = __fdividef(p[h], s[h]);
    asm volatile("s_waitcnt lgkmcnt(0)" ::: "memory");

    // --- gather: lane = (sub=edge parity, fl=feature quad) ---
    int sub = lane >> 5, fl = lane & 31;
    int hh2 = fl >> 3;                 // head of this feature quad
    float b0 = 0.f, b1 = 0.f, b2 = 0.f, b3 = 0.f;
#pragma unroll 4
    for (int j = sub; j < deg; j += 2) {
      int snj = scol[wave][j];
      float alpha = salpha[wave][hh2][j];
      uint2 pck = *(const uint2*)&Hb[(size_t)snj * DD + fl * 4];
      b0 = __fmaf_rn(alpha, __uint_as_float(pck.x << 16), b0);
      b1 = __fmaf_rn(alpha, __uint_as_float(pck.x & 0xFFFF0000u), b1);
      b2 = __fmaf_rn(alpha, __uint_as_float(pck.y << 16), b2);
      b3 = __fmaf_rn(alpha, __uint_as_float(pck.y & 0xFFFF0000u), b3);
    }
    // combine edge-parity halves (lane L and L^32 hold the same features)
    b0 += __shfl_xor(b0, 32);
    b1 += __shfl_xor(b1, 32);
    b2 += __shfl_xor(b2, 32);
    b3 += __shfl_xor(b3, 32);

    // bias + LayerNorm + LeakyReLU (values duplicated across halves; reduce within 32)
    int f4 = fl * 4;
    float4 bi = *(const float4*)&bias[f4];
    float x0 = b0 + bi.x, x1 = b1 + bi.y, x2 = b2 + bi.z, x3 = b3 + bi.w;
    float sum = x0 + x1 + x2 + x3;
    float ssq = x0 * x0 + x1 * x1 + x2 * x2 + x3 * x3;
#pragma unroll
    for (int off = 16; off; off >>= 1) {
      sum += __shfl_xor(sum, off);
      ssq += __shfl_xor(ssq, off);
    }
    float mu = sum * (1.f / 128.f);
    float var = ssq * (1.f / 128.f) - mu * mu;
    float rstd = rsqrtf(var + 1e-5f);
    float4 ga = *(const float4*)&gamma[f4];
    float4 be = *(const float4*)&beta[f4];
    float y0 = (x0 - mu) * rstd * ga.x + be.x;
    float y1 = (x1 - mu) * rstd * ga.y + be.y;
    float y2 = (x2 - mu) * rstd * ga.z + be.z;
    float y3 = (x3 - mu) * rstd * ga.w + be.w;
    y0 = y0 > 0.f ? y0 : 0.1f * y0;
    y1 = y1 > 0.f ? y1 : 0.1f * y1;
    y2 = y2 > 0.f ? y2 : 0.1f * y2;
    y3 = y3 > 0.f ? y3 : 0.1f * y3;
    if (sub == 0) {
      float4 o = {y0, y1, y2, y3};
      *(float4*)&outb[(size_t)n * DD + f4] = o;
    }
  } else {
    // --- fallback: online two-pass, 2 feats/lane (proven; ~never taken) ---
    int hh = lane >> 4;
    float a0 = 0.f, a1 = 0.f;
    float m[4] = {NEG_SENT, NEG_SENT, NEG_SENT, NEG_SENT};
    float s[4] = {0.f, 0.f, 0.f, 0.f};
    for (int e = e0 + lane; e < e1; e += 64) {
      int sn = col[e];
      float4 as = *(const float4*)&als[(size_t)sn * 4];
      float v[4] = {as.x + ad.x, as.y + ad.y, as.z + ad.z, as.w + ad.w};
#pragma unroll
      for (int h = 0; h < 4; ++h) {
        float vvv = v[h] > 0.f ? v[h] : 0.2f * v[h];
        if (vvv > m[h]) { s[h] = s[h] * __expf(m[h] - vvv) + 1.f; m[h] = vvv; }
        else             s[h] += __expf(vvv - m[h]);
      }
    }
#pragma unroll
    for (int off = 32; off; off >>= 1) {
#pragma unroll
      for (int h = 0; h < 4; ++h) {
        float mo = __shfl_xor(m[h], off);
        float so = __shfl_xor(s[h], off);
        float M = fmaxf(m[h], mo);
        s[h] = s[h] * __expf(m[h] - M) + so * __expf(mo - M);
        m[h] = M;
      }
    }
    float mh = m[hh];
    float rdh = __fdividef(1.f, s[hh]);
    float adh = (hh == 0) ? ad.x : (hh == 1) ? ad.y : (hh == 2) ? ad.z : ad.w;
    int e = e0;
    while (e < e1) {
      int cnt = min(64, e1 - e);
      int myS = (lane < cnt) ? col[e + lane] : 0;
      for (int j = 0; j < cnt; ++j) {
        int sn = __shfl(myS, j);
        float v = als[(size_t)sn * 4 + hh] + adh;
        v = v > 0.f ? v : 0.2f * v;
        float alpha = __expf(v - mh) * rdh;
        unsigned pck = *(const unsigned*)&Hb[(size_t)sn * DD + 2 * lane];
        float h0 = __uint_as_float(pck << 16);
        float h1 = __uint_as_float(pck & 0xFFFF0000u);
        a0 = __fmaf_rn(alpha, h0, a0);
        a1 = __fmaf_rn(alpha, h1, a1);
      }
      e += cnt;
    }
    int f0 = 2 * lane, f1 = 2 * lane + 1;
    float x0 = a0 + bias[f0], x1 = a1 + bias[f1];
    float sum = x0 + x1, ssq = x0 * x0 + x1 * x1;
#pragma unroll
    for (int off = 32; off; off >>= 1) {
      sum += __shfl_xor(sum, off);
      ssq += __shfl_xor(ssq, off);
    }
    float mu = sum * (1.f / 128.f);
    float var = ssq * (1.f / 128.f) - mu * mu;
    float rstd = rsqrtf(var + 1e-5f);
    float y0 = (x0 - mu) * rstd * gamma[f0] + beta[f0];
    float y1 = (x1 - mu) * rstd * gamma[f1] + beta[f1];
    y0 = y0 > 0.f ? y0 : 0.1f * y0;
    y1 = y1 > 0.f ? y1 : 0.1f * y1;
    float2 o = {y0, y1};
    *(float2*)&outb[(size_t)n * DD + f0] = o;
  }
}

// ---- Fused pooling + output GEMM (256 threads: node range and k-range split) ----
__global__ __launch_bounds__(256) void poolout_k(const float* __restrict__ xin,
                                                 const int* __restrict__ gs,
                                                 const float* __restrict__ Wout,
                                                 const float* __restrict__ bout,
                                                 float* __restrict__ out) {
  __shared__ float sp[256];
  __shared__ float r0[256], r1[256];
  int g = blockIdx.x, t = threadIdx.x;
  int f = t & 127, half = t >> 7;
  int n0 = gs[g], n1 = gs[g + 1];
  int cnt = n1 - n0;
  int mid = n0 + (cnt >> 1);
  int a = half ? mid : n0;
  int b = half ? n1 : mid;
  float mx = NEG_SENT, sm = 0.f;
  for (int n = a; n < b; ++n) {
    float v = xin[(size_t)n * DD + f];
    mx = fmaxf(mx, v);
    sm += v;
  }
  r0[t] = mx;
  r1[t] = sm;
  __syncthreads();
  if (t < 128) {
    sp[t] = fmaxf(r0[t], r0[t + 128]);
    sp[128 + t] = (r1[t] + r1[t + 128]) / fmaxf((float)cnt, 1.f);
  }
  __syncthreads();
  float acc = half ? 0.f : bout[f];
  int k0 = half * 128;
#pragma unroll 8
  for (int k = k0; k < k0 + 128; ++k) acc = __fmaf_rn(sp[k], Wout[k * 128 + f], acc);
  r0[t] = acc;
  __syncthreads();
  if (t < 128) out[(size_t)g * 128 + f] = r0[t] + r0[t + 128];
}

extern "C" void kernel_launch(void* const* d_in, const int* in_sizes, int n_in,
                              void* d_out, int out_size, void* d_ws, size_t ws_size,
                              hipStream_t stream) {
  const float* x       = (const float*)d_in[0];
  const int*   ei      = (const int*)d_in[1];
  const int*   batch   = (const int*)d_in[2];
  const float* W       = (const float*)d_in[3];
  const float* att_src = (const float*)d_in[4];
  const float* att_dst = (const float*)d_in[5];
  const float* bias    = (const float*)d_in[6];
  const float* gamma   = (const float*)d_in[7];
  const float* beta    = (const float*)d_in[8];
  const float* Wout    = (const float*)d_in[9];
  const float* bout    = (const float*)d_in[10];
  float* out = (float*)d_out;

  char* ws = (char*)d_ws;
  unsigned short* Hb = (unsigned short*)ws; ws += (size_t)NN * DD * 2;
  float* AB   = (float*)ws; ws += (size_t)NN * DD * 4;
  float* als  = (float*)ws; ws += (size_t)NN * HH * 4;
  float* ald  = (float*)ws; ws += (size_t)NN * HH * 4;
  int*   rp   = (int*)ws;   ws += (size_t)(NN + 1) * 4;
  int*   deg  = (int*)ws;   ws += (size_t)NN * 4;      // reused as scatter cursor
  int*   col  = (int*)ws;   ws += (size_t)ETOT * 4;
  int*   gs   = (int*)ws;   ws += (size_t)(GG + 1) * 4;
  int*   bsum = (int*)ws;   ws += (size_t)NBLK * 4;
  int*   boff = (int*)ws;   ws += (size_t)NBLK * 4;

  // ---- CSR build + graph offsets (once) ----
  hipMemsetAsync(deg, 0, (size_t)NN * 4, stream);
  deg_k<<<CSRB, 256, 0, stream>>>(ei, deg);
  scanA_k<<<NBLK, 256, 0, stream>>>(deg, rp, bsum);
  scanB_k<<<1, 256, 0, stream>>>(bsum, boff);
  scanC_k<<<NBLK, 256, 0, stream>>>(rp, boff, deg);
  scatter_k<<<CSRB, 256, 0, stream>>>(ei, deg, col);
  gstart_k<<<(GG + 1 + 63) / 64, 64, 0, stream>>>(batch, gs);

  // ---- layers ----
  const float* in = x;
  for (int l = 0; l < LL; ++l) {
    gemm_al_k<<<(NN + 31) / 32, 256, 0, stream>>>(in, W + (size_t)l * DD * DD,
                                                  att_src + l * DD, att_dst + l * DD,
                                                  Hb, als, ald);
    agg_k<<<(NN + 3) / 4, 256, 0, stream>>>(rp, col, als, ald, Hb,
                                            bias + l * DD, gamma + l * DD, beta + l * DD, AB);
    in = AB;
  }

  // ---- fused pooling + output GEMM ----
  poolout_k<<<GG, 256, 0, stream>>>(AB, gs, Wout, bout, out);
}